// Round 1
// baseline (262.517 us; speedup 1.0000x reference)
//
#include <hip/hip_runtime.h>

// Malvar-He-Cutler demosaic. x: (N,1,H,W) fp32 bayer mosaic -> out: (N,3,H,W) fp32.
// Memory-bound: 64 MB in + 192 MB out -> ~41 us floor at 6.3 TB/s.

constexpr int H = 1024, W = 1024;
constexpr int TILE_W = 128, TILE_H = 8;
constexpr int LDS_W = TILE_W + 4;   // 132 floats = 528 B = 33*16 B -> rows stay 16B-aligned
constexpr int LDS_H = TILE_H + 4;   // 12

__global__ __launch_bounds__(256) void demosaic_kernel(
    const float* __restrict__ xin_all, const int* __restrict__ bp,
    float* __restrict__ out)
{
    __shared__ float tile[LDS_H][LDS_W];

    const int tx = threadIdx.x;            // 0..31
    const int ty = threadIdx.y;            // 0..7
    const int tid = ty * 32 + tx;
    const int x0 = blockIdx.x * TILE_W;
    const int y0 = blockIdx.y * TILE_H;
    const int n  = blockIdx.z;

    // Bayer pattern -> parity flips (uniform scalar loads, L1-resident).
    // RGGB(0,1,1,2): fi=0,fj=0  GRBG(1,0,2,1): fi=0,fj=1
    // GBRG(1,2,0,1): fi=1,fj=0  BGGR(2,1,1,0): fi=1,fj=1
    const int p0 = bp[0], p1 = bp[1];
    const int fi = (p0 == 2) || (p0 == 1 && p1 == 2);
    const int fj = (p0 == 2) || (p0 == 1 && p1 == 0);

    const float* __restrict__ xin = xin_all + (size_t)n * H * W;

    // Stage 132x12 tile with clamped coords (edge-replicate padding).
    #pragma unroll
    for (int idx = tid; idx < LDS_H * LDS_W; idx += 256) {
        const int r = idx / LDS_W;
        const int c = idx - r * LDS_W;
        const int gy = min(max(y0 + r - 2, 0), H - 1);
        const int gx = min(max(x0 + c - 2, 0), W - 1);
        tile[r][c] = xin[gy * W + gx];
    }
    __syncthreads();

    // 5x8 register window covering this thread's 4 pixels (+/-2 halo).
    const int xs = tx * 4;
    float w[5][8];
    #pragma unroll
    for (int r = 0; r < 5; ++r) {
        const float4 a = *(const float4*)&tile[ty + r][xs];
        const float4 b = *(const float4*)&tile[ty + r][xs + 4];
        w[r][0] = a.x; w[r][1] = a.y; w[r][2] = a.z; w[r][3] = a.w;
        w[r][4] = b.x; w[r][5] = b.y; w[r][6] = b.z; w[r][7] = b.w;
    }

    const int y  = y0 + ty;
    const int qi = (y & 1) ^ fi;

    float r4[4], g4[4], b4[4];
    #pragma unroll
    for (int p = 0; p < 4; ++p) {
        const float c   = w[2][p + 2];
        const float up  = w[1][p + 2], dn  = w[3][p + 2];
        const float lf  = w[2][p + 1], rt  = w[2][p + 3];
        const float up2 = w[0][p + 2], dn2 = w[4][p + 2];
        const float lf2 = w[2][p + 0], rt2 = w[2][p + 4];
        const float dg  = w[1][p + 1] + w[1][p + 3] + w[3][p + 1] + w[3][p + 3];

        const float axH = lf2 + rt2;          // horizontal +/-2
        const float axV = up2 + dn2;          // vertical +/-2
        const float ax  = axH + axV;
        const float crossHV = (up + dn) + (lf + rt);

        // K0: 8c +4(cross) -2(ax)          -> G at R/B sites
        // K1: 12c +4(diag) -3(ax)          -> R/B at opposite bayer site
        // K2: 10c +8(l+r) -2(axH+diag) +axV -> R/B at G site, same row
        // K3: 10c +8(u+d) -2(axV+diag) +axH -> R/B at G site, same col
        const float s0 = (8.0f  * c + 4.0f * crossHV  - 2.0f * ax) * 0.0625f;
        const float s1 = (12.0f * c + 4.0f * dg       - 3.0f * ax) * 0.0625f;
        const float s2 = (10.0f * c + 8.0f * (lf + rt) - 2.0f * (axH + dg) + axV) * 0.0625f;
        const float s3 = (10.0f * c + 8.0f * (up + dn) - 2.0f * (axV + dg) + axH) * 0.0625f;

        // x parity == p&1 (x0 and xs are even)
        const int qj = (p & 1) ^ fj;
        const int qt = (qi << 1) | qj;
        // RGGB gather table: (0,0): R=c  G=s0 B=s1 | (0,1): R=s2 G=c B=s3
        //                    (1,0): R=s3 G=c B=s2  | (1,1): R=s1 G=s0 B=c
        r4[p] = (qt == 0) ? c  : (qt == 1) ? s2 : (qt == 2) ? s3 : s1;
        g4[p] = (qi == qj) ? s0 : c;
        b4[p] = (qt == 0) ? s1 : (qt == 1) ? s3 : (qt == 2) ? s2 : c;
    }

    const size_t colbase = (size_t)(x0 + xs);
    float4* __restrict__ oR = (float4*)(out + ((size_t)(n * 3 + 0) * H + y) * W + colbase);
    float4* __restrict__ oG = (float4*)(out + ((size_t)(n * 3 + 1) * H + y) * W + colbase);
    float4* __restrict__ oB = (float4*)(out + ((size_t)(n * 3 + 2) * H + y) * W + colbase);
    *oR = make_float4(r4[0], r4[1], r4[2], r4[3]);
    *oG = make_float4(g4[0], g4[1], g4[2], g4[3]);
    *oB = make_float4(b4[0], b4[1], b4[2], b4[3]);
}

extern "C" void kernel_launch(void* const* d_in, const int* in_sizes, int n_in,
                              void* d_out, int out_size, void* d_ws, size_t ws_size,
                              hipStream_t stream) {
    const float* x  = (const float*)d_in[0];
    const int*   bp = (const int*)d_in[1];
    float* out = (float*)d_out;
    const int N = in_sizes[0] / (H * W);   // 16
    dim3 grid(W / TILE_W, H / TILE_H, N);  // (8, 128, 16)
    dim3 block(32, 8, 1);
    demosaic_kernel<<<grid, block, 0, stream>>>(x, bp, out);
}

// Round 2
// 257.967 us; speedup vs baseline: 1.0176x; 1.0176x over previous
//
#include <hip/hip_runtime.h>

// Malvar-He-Cutler demosaic. x: (N,1,H,W) fp32 bayer mosaic -> out: (N,3,H,W) fp32.
// Memory-bound: 64 MB in + 192 MB out -> ~41 us floor at 6.3 TB/s.
// R1: 128x32 tile, 4 rows/thread (8x8 reg window) -> halo over-fetch 1.55x -> 1.16x,
//     LDS read 40 B/px -> 16 B/px, 4096 blocks.

constexpr int H = 1024, W = 1024;
constexpr int TILE_W = 128, TILE_H = 32;
constexpr int LDS_W = TILE_W + 4;   // 132 floats = 528 B = 33*16 B -> rows stay 16B-aligned
constexpr int LDS_H = TILE_H + 4;   // 36 -> 19,008 B LDS

__global__ __launch_bounds__(256) void demosaic_kernel(
    const float* __restrict__ xin_all, const int* __restrict__ bp,
    float* __restrict__ out)
{
    __shared__ float tile[LDS_H][LDS_W];

    const int tx = threadIdx.x;            // 0..31 -> 4 px wide
    const int ty = threadIdx.y;            // 0..7  -> 4 rows each
    const int tid = ty * 32 + tx;
    const int x0 = blockIdx.x * TILE_W;
    const int y0 = blockIdx.y * TILE_H;
    const int n  = blockIdx.z;

    // Bayer pattern -> parity flips (uniform scalar loads, L1-resident).
    // RGGB(0,1,1,2): fi=0,fj=0  GRBG(1,0,2,1): fi=0,fj=1
    // GBRG(1,2,0,1): fi=1,fj=0  BGGR(2,1,1,0): fi=1,fj=1
    const int p0 = bp[0], p1 = bp[1];
    const int fi = (p0 == 2) || (p0 == 1 && p1 == 2);
    const int fj = (p0 == 2) || (p0 == 1 && p1 == 0);

    const float* __restrict__ xin = xin_all + (size_t)n * H * W;

    // Stage 132x36 tile with clamped coords (edge-replicate padding).
    for (int idx = tid; idx < LDS_H * LDS_W; idx += 256) {
        const int r = idx / LDS_W;
        const int c = idx - r * LDS_W;
        const int gy = min(max(y0 + r - 2, 0), H - 1);
        const int gx = min(max(x0 + c - 2, 0), W - 1);
        tile[r][c] = xin[gy * W + gx];
    }
    __syncthreads();

    const int xs  = tx * 4;
    const int ry0 = ty * 4;

    // 8x8 register window covering this thread's 4x4 patch (+/-2 halo).
    float w[8][8];
    #pragma unroll
    for (int r = 0; r < 8; ++r) {
        const float4 a = *(const float4*)&tile[ry0 + r][xs];
        const float4 b = *(const float4*)&tile[ry0 + r][xs + 4];
        w[r][0] = a.x; w[r][1] = a.y; w[r][2] = a.z; w[r][3] = a.w;
        w[r][4] = b.x; w[r][5] = b.y; w[r][6] = b.z; w[r][7] = b.w;
    }

    #pragma unroll
    for (int dr = 0; dr < 4; ++dr) {
        // y = y0 + ry0 + dr; y0, ry0 even -> row parity = dr&1
        const int qi = (dr & 1) ^ fi;

        float r4[4], g4[4], b4[4];
        #pragma unroll
        for (int p = 0; p < 4; ++p) {
            const float c   = w[dr + 2][p + 2];
            const float up  = w[dr + 1][p + 2], dn  = w[dr + 3][p + 2];
            const float lf  = w[dr + 2][p + 1], rt  = w[dr + 2][p + 3];
            const float up2 = w[dr + 0][p + 2], dn2 = w[dr + 4][p + 2];
            const float lf2 = w[dr + 2][p + 0], rt2 = w[dr + 2][p + 4];
            const float dg  = w[dr + 1][p + 1] + w[dr + 1][p + 3]
                            + w[dr + 3][p + 1] + w[dr + 3][p + 3];

            const float axH = lf2 + rt2;          // horizontal +/-2
            const float axV = up2 + dn2;          // vertical +/-2
            const float ax  = axH + axV;
            const float crossHV = (up + dn) + (lf + rt);

            // K0: 8c +4(cross) -2(ax)           -> G at R/B sites
            // K1: 12c +4(diag) -3(ax)           -> R/B at opposite bayer site
            // K2: 10c +8(l+r) -2(axH+diag) +axV -> R/B at G site, same row
            // K3: 10c +8(u+d) -2(axV+diag) +axH -> R/B at G site, same col
            const float s0 = (8.0f  * c + 4.0f * crossHV   - 2.0f * ax) * 0.0625f;
            const float s1 = (12.0f * c + 4.0f * dg        - 3.0f * ax) * 0.0625f;
            const float s2 = (10.0f * c + 8.0f * (lf + rt) - 2.0f * (axH + dg) + axV) * 0.0625f;
            const float s3 = (10.0f * c + 8.0f * (up + dn) - 2.0f * (axV + dg) + axH) * 0.0625f;

            // x parity == p&1 (x0 and xs are even)
            const int qj = (p & 1) ^ fj;
            const int qt = (qi << 1) | qj;
            // RGGB gather: (0,0): R=c  G=s0 B=s1 | (0,1): R=s2 G=c B=s3
            //              (1,0): R=s3 G=c B=s2  | (1,1): R=s1 G=s0 B=c
            r4[p] = (qt == 0) ? c  : (qt == 1) ? s2 : (qt == 2) ? s3 : s1;
            g4[p] = (qi == qj) ? s0 : c;
            b4[p] = (qt == 0) ? s1 : (qt == 1) ? s3 : (qt == 2) ? s2 : c;
        }

        const int y = y0 + ry0 + dr;
        const size_t colbase = (size_t)(x0 + xs);
        float4* __restrict__ oR = (float4*)(out + ((size_t)(n * 3 + 0) * H + y) * W + colbase);
        float4* __restrict__ oG = (float4*)(out + ((size_t)(n * 3 + 1) * H + y) * W + colbase);
        float4* __restrict__ oB = (float4*)(out + ((size_t)(n * 3 + 2) * H + y) * W + colbase);
        *oR = make_float4(r4[0], r4[1], r4[2], r4[3]);
        *oG = make_float4(g4[0], g4[1], g4[2], g4[3]);
        *oB = make_float4(b4[0], b4[1], b4[2], b4[3]);
    }
}

extern "C" void kernel_launch(void* const* d_in, const int* in_sizes, int n_in,
                              void* d_out, int out_size, void* d_ws, size_t ws_size,
                              hipStream_t stream) {
    const float* x  = (const float*)d_in[0];
    const int*   bp = (const int*)d_in[1];
    float* out = (float*)d_out;
    const int N = in_sizes[0] / (H * W);   // 16
    dim3 grid(W / TILE_W, H / TILE_H, N);  // (8, 32, 16)
    dim3 block(32, 8, 1);
    demosaic_kernel<<<grid, block, 0, stream>>>(x, bp, out);
}

// Round 4
// 248.909 us; speedup vs baseline: 1.0547x; 1.0364x over previous
//
#include <hip/hip_runtime.h>

// Malvar-He-Cutler demosaic. x: (N,1,H,W) fp32 bayer mosaic -> out: (N,3,H,W) fp32.
// Memory-bound: 64 MB in + 192 MB out -> ~41 us floor at 6.3 TB/s.
// R1: 128x32 tile, 4 rows/thread (8x8 reg window), halo over-fetch 1.16x.
// R2/R3: float4 staging (global dwordx4 -> ds_write_b128), nontemporal output
//        stores via ext_vector_type (write-once, keep L2 for input).

constexpr int H = 1024, W = 1024;
constexpr int TILE_W = 128, TILE_H = 32;
constexpr int LDS_W = TILE_W + 4;   // 132 floats = 528 B = 33*16 B -> rows stay 16B-aligned
constexpr int LDS_H = TILE_H + 4;   // 36 -> 19,008 B LDS
constexpr int CHUNKS_PER_ROW = LDS_W / 4;            // 33
constexpr int N_CHUNKS = CHUNKS_PER_ROW * LDS_H;     // 1188

typedef float v4f __attribute__((ext_vector_type(4)));  // native vector: ok for nontemporal builtin

__global__ __launch_bounds__(256) void demosaic_kernel(
    const float* __restrict__ xin_all, const int* __restrict__ bp,
    float* __restrict__ out)
{
    __shared__ float tile[LDS_H][LDS_W];

    const int tx = threadIdx.x;            // 0..31 -> 4 px wide
    const int ty = threadIdx.y;            // 0..7  -> 4 rows each
    const int tid = ty * 32 + tx;
    const int x0 = blockIdx.x * TILE_W;
    const int y0 = blockIdx.y * TILE_H;
    const int n  = blockIdx.z;

    // Bayer pattern -> parity flips (uniform scalar loads, L1-resident).
    // RGGB(0,1,1,2): fi=0,fj=0  GRBG(1,0,2,1): fi=0,fj=1
    // GBRG(1,2,0,1): fi=1,fj=0  BGGR(2,1,1,0): fi=1,fj=1
    const int p0 = bp[0], p1 = bp[1];
    const int fi = (p0 == 2) || (p0 == 1 && p1 == 2);
    const int fj = (p0 == 2) || (p0 == 1 && p1 == 0);

    const float* __restrict__ xin = xin_all + (size_t)n * H * W;

    // Stage 132x36 tile as float4 chunks. LDS col c <-> global col x0-2+c.
    // Chunk k covers LDS cols 4k..4k+3 (16B-aligned ds_write_b128); global
    // address is 8B-aligned (x0-2) -- fine for global_load_dwordx4.
    const int gx0 = x0 - 2;
    for (int idx = tid; idx < N_CHUNKS; idx += 256) {
        const int r = idx / CHUNKS_PER_ROW;           // magic-mul
        const int k = idx - r * CHUNKS_PER_ROW;
        const int gy = min(max(y0 + r - 2, 0), H - 1);
        const int gx = gx0 + 4 * k;
        const float* __restrict__ rowp = xin + (size_t)gy * W;
        v4f v;
        if (gx >= 0 && gx + 3 < W) {                  // interior (all but 2 block-cols)
            v = *(const v4f*)(rowp + gx);
        } else {                                      // edge-replicate clamp
            v.x = rowp[min(max(gx + 0, 0), W - 1)];
            v.y = rowp[min(max(gx + 1, 0), W - 1)];
            v.z = rowp[min(max(gx + 2, 0), W - 1)];
            v.w = rowp[min(max(gx + 3, 0), W - 1)];
        }
        *(v4f*)&tile[r][4 * k] = v;
    }
    __syncthreads();

    const int xs  = tx * 4;
    const int ry0 = ty * 4;

    // 8x8 register window covering this thread's 4x4 patch (+/-2 halo).
    float w[8][8];
    #pragma unroll
    for (int r = 0; r < 8; ++r) {
        const v4f a = *(const v4f*)&tile[ry0 + r][xs];
        const v4f b = *(const v4f*)&tile[ry0 + r][xs + 4];
        w[r][0] = a.x; w[r][1] = a.y; w[r][2] = a.z; w[r][3] = a.w;
        w[r][4] = b.x; w[r][5] = b.y; w[r][6] = b.z; w[r][7] = b.w;
    }

    #pragma unroll
    for (int dr = 0; dr < 4; ++dr) {
        // y = y0 + ry0 + dr; y0, ry0 even -> row parity = dr&1
        const int qi = (dr & 1) ^ fi;

        float r4[4], g4[4], b4[4];
        #pragma unroll
        for (int p = 0; p < 4; ++p) {
            const float c   = w[dr + 2][p + 2];
            const float up  = w[dr + 1][p + 2], dn  = w[dr + 3][p + 2];
            const float lf  = w[dr + 2][p + 1], rt  = w[dr + 2][p + 3];
            const float up2 = w[dr + 0][p + 2], dn2 = w[dr + 4][p + 2];
            const float lf2 = w[dr + 2][p + 0], rt2 = w[dr + 2][p + 4];
            const float dg  = w[dr + 1][p + 1] + w[dr + 1][p + 3]
                            + w[dr + 3][p + 1] + w[dr + 3][p + 3];

            const float axH = lf2 + rt2;          // horizontal +/-2
            const float axV = up2 + dn2;          // vertical +/-2
            const float ax  = axH + axV;
            const float crossHV = (up + dn) + (lf + rt);

            // K0: 8c +4(cross) -2(ax)           -> G at R/B sites
            // K1: 12c +4(diag) -3(ax)           -> R/B at opposite bayer site
            // K2: 10c +8(l+r) -2(axH+diag) +axV -> R/B at G site, same row
            // K3: 10c +8(u+d) -2(axV+diag) +axH -> R/B at G site, same col
            const float s0 = (8.0f  * c + 4.0f * crossHV   - 2.0f * ax) * 0.0625f;
            const float s1 = (12.0f * c + 4.0f * dg        - 3.0f * ax) * 0.0625f;
            const float s2 = (10.0f * c + 8.0f * (lf + rt) - 2.0f * (axH + dg) + axV) * 0.0625f;
            const float s3 = (10.0f * c + 8.0f * (up + dn) - 2.0f * (axV + dg) + axH) * 0.0625f;

            // x parity == p&1 (x0 and xs are even)
            const int qj = (p & 1) ^ fj;
            const int qt = (qi << 1) | qj;
            // RGGB gather: (0,0): R=c  G=s0 B=s1 | (0,1): R=s2 G=c B=s3
            //              (1,0): R=s3 G=c B=s2  | (1,1): R=s1 G=s0 B=c
            r4[p] = (qt == 0) ? c  : (qt == 1) ? s2 : (qt == 2) ? s3 : s1;
            g4[p] = (qi == qj) ? s0 : c;
            b4[p] = (qt == 0) ? s1 : (qt == 1) ? s3 : (qt == 2) ? s2 : c;
        }

        const int y = y0 + ry0 + dr;
        const size_t colbase = (size_t)(x0 + xs);
        v4f* __restrict__ oR = (v4f*)(out + ((size_t)(n * 3 + 0) * H + y) * W + colbase);
        v4f* __restrict__ oG = (v4f*)(out + ((size_t)(n * 3 + 1) * H + y) * W + colbase);
        v4f* __restrict__ oB = (v4f*)(out + ((size_t)(n * 3 + 2) * H + y) * W + colbase);
        v4f vR = { r4[0], r4[1], r4[2], r4[3] };
        v4f vG = { g4[0], g4[1], g4[2], g4[3] };
        v4f vB = { b4[0], b4[1], b4[2], b4[3] };
        __builtin_nontemporal_store(vR, oR);
        __builtin_nontemporal_store(vG, oG);
        __builtin_nontemporal_store(vB, oB);
    }
}

extern "C" void kernel_launch(void* const* d_in, const int* in_sizes, int n_in,
                              void* d_out, int out_size, void* d_ws, size_t ws_size,
                              hipStream_t stream) {
    const float* x  = (const float*)d_in[0];
    const int*   bp = (const int*)d_in[1];
    float* out = (float*)d_out;
    const int N = in_sizes[0] / (H * W);   // 16
    dim3 grid(W / TILE_W, H / TILE_H, N);  // (8, 32, 16)
    dim3 block(32, 8, 1);
    demosaic_kernel<<<grid, block, 0, stream>>>(x, bp, out);
}

// Round 5
// 245.128 us; speedup vs baseline: 1.0709x; 1.0154x over previous
//
#include <hip/hip_runtime.h>

// Malvar-He-Cutler demosaic. x: (N,1,H,W) fp32 bayer mosaic -> out: (N,3,H,W) fp32.
// Memory-bound: 64 MB in + 192 MB out -> ~41 us floor at 6.3 TB/s.
// R1: 128x32 tile, 4 rows/thread (8x8 reg window), halo over-fetch 1.16x.
// R2/R3: float4 staging, nontemporal output stores (write-once).
// R5: global_load_lds 16B DMA staging (no VGPR round-trip); edge fixup only in
//     the 2/8 boundary block-columns (block-uniform branch).

constexpr int H = 1024, W = 1024;
constexpr int TILE_W = 128, TILE_H = 32;
constexpr int LDS_W = TILE_W + 4;   // 132 floats = 528 B = 33*16 B -> rows stay 16B-aligned
constexpr int LDS_H = TILE_H + 4;   // 36 -> 19,008 B LDS
constexpr int CHUNKS_PER_ROW = LDS_W / 4;            // 33
constexpr int N_CHUNKS = CHUNKS_PER_ROW * LDS_H;     // 1188

typedef float v4f __attribute__((ext_vector_type(4)));
typedef __attribute__((address_space(1))) const unsigned int gu32;
typedef __attribute__((address_space(3))) unsigned int lu32;

__global__ __launch_bounds__(256) void demosaic_kernel(
    const float* __restrict__ xin_all, const int* __restrict__ bp,
    float* __restrict__ out)
{
    __shared__ float tile[LDS_H][LDS_W];

    const int tx = threadIdx.x;            // 0..31 -> 4 px wide
    const int ty = threadIdx.y;            // 0..7  -> 4 rows each
    const int tid = ty * 32 + tx;
    const int x0 = blockIdx.x * TILE_W;
    const int y0 = blockIdx.y * TILE_H;
    const int n  = blockIdx.z;

    // Bayer pattern -> parity flips (uniform scalar loads, L1-resident).
    // RGGB(0,1,1,2): fi=0,fj=0  GRBG(1,0,2,1): fi=0,fj=1
    // GBRG(1,2,0,1): fi=1,fj=0  BGGR(2,1,1,0): fi=1,fj=1
    const int p0 = bp[0], p1 = bp[1];
    const int fi = (p0 == 2) || (p0 == 1 && p1 == 2);
    const int fj = (p0 == 2) || (p0 == 1 && p1 == 0);

    const float* __restrict__ xin = xin_all + (size_t)n * H * W;

    // Stage 132x36 tile via 16B global->LDS DMA. Chunk idx -> LDS offset idx*16:
    // per wave this is uniform base + lane*16 (the HW requirement). Per-lane
    // global addresses are arbitrary (gather). Edge chunks (k==0 at x0==0,
    // k==32 at x0==896) get a safe in-bounds address now, exact values after
    // the barrier.
    const int gx0 = x0 - 2;
    for (int idx = tid; idx < N_CHUNKS; idx += 256) {
        const int r = idx / CHUNKS_PER_ROW;           // magic-mul
        const int k = idx - r * CHUNKS_PER_ROW;
        const int gy = min(max(y0 + r - 2, 0), H - 1);
        const int gx = min(max(gx0 + 4 * k, 0), W - 4);
        const float* src = xin + (size_t)gy * W + gx;
        __builtin_amdgcn_global_load_lds((gu32*)src, (lu32*)&tile[r][4 * k], 16, 0, 0);
    }
    __syncthreads();   // drains vmcnt -> all DMA complete

    const bool left_edge  = (x0 == 0);
    const bool right_edge = (x0 == W - TILE_W);
    if (left_edge || right_edge) {                    // block-uniform
        if (tid < LDS_H) {
            const int r  = tid;
            const int gy = min(max(y0 + r - 2, 0), H - 1);
            const float* __restrict__ rowp = xin + (size_t)gy * W;
            if (left_edge) {   // chunk k=0: cols 0..3 = global -2..1 clamped
                tile[r][0] = rowp[0]; tile[r][1] = rowp[0];
                tile[r][2] = rowp[0]; tile[r][3] = rowp[1];
            }
            if (right_edge) {  // chunk k=32: cols 128..131 = global 1022..1025 clamped
                tile[r][128] = rowp[W - 2]; tile[r][129] = rowp[W - 1];
                tile[r][130] = rowp[W - 1]; tile[r][131] = rowp[W - 1];
            }
        }
        __syncthreads();
    }

    const int xs  = tx * 4;
    const int ry0 = ty * 4;

    // 8x8 register window covering this thread's 4x4 patch (+/-2 halo).
    float w[8][8];
    #pragma unroll
    for (int r = 0; r < 8; ++r) {
        const v4f a = *(const v4f*)&tile[ry0 + r][xs];
        const v4f b = *(const v4f*)&tile[ry0 + r][xs + 4];
        w[r][0] = a.x; w[r][1] = a.y; w[r][2] = a.z; w[r][3] = a.w;
        w[r][4] = b.x; w[r][5] = b.y; w[r][6] = b.z; w[r][7] = b.w;
    }

    #pragma unroll
    for (int dr = 0; dr < 4; ++dr) {
        // y = y0 + ry0 + dr; y0, ry0 even -> row parity = dr&1
        const int qi = (dr & 1) ^ fi;

        float r4[4], g4[4], b4[4];
        #pragma unroll
        for (int p = 0; p < 4; ++p) {
            const float c   = w[dr + 2][p + 2];
            const float up  = w[dr + 1][p + 2], dn  = w[dr + 3][p + 2];
            const float lf  = w[dr + 2][p + 1], rt  = w[dr + 2][p + 3];
            const float up2 = w[dr + 0][p + 2], dn2 = w[dr + 4][p + 2];
            const float lf2 = w[dr + 2][p + 0], rt2 = w[dr + 2][p + 4];
            const float dg  = w[dr + 1][p + 1] + w[dr + 1][p + 3]
                            + w[dr + 3][p + 1] + w[dr + 3][p + 3];

            const float axH = lf2 + rt2;          // horizontal +/-2
            const float axV = up2 + dn2;          // vertical +/-2
            const float ax  = axH + axV;
            const float crossHV = (up + dn) + (lf + rt);

            // K0: 8c +4(cross) -2(ax)           -> G at R/B sites
            // K1: 12c +4(diag) -3(ax)           -> R/B at opposite bayer site
            // K2: 10c +8(l+r) -2(axH+diag) +axV -> R/B at G site, same row
            // K3: 10c +8(u+d) -2(axV+diag) +axH -> R/B at G site, same col
            const float s0 = (8.0f  * c + 4.0f * crossHV   - 2.0f * ax) * 0.0625f;
            const float s1 = (12.0f * c + 4.0f * dg        - 3.0f * ax) * 0.0625f;
            const float s2 = (10.0f * c + 8.0f * (lf + rt) - 2.0f * (axH + dg) + axV) * 0.0625f;
            const float s3 = (10.0f * c + 8.0f * (up + dn) - 2.0f * (axV + dg) + axH) * 0.0625f;

            // x parity == p&1 (x0 and xs are even)
            const int qj = (p & 1) ^ fj;
            const int qt = (qi << 1) | qj;
            // RGGB gather: (0,0): R=c  G=s0 B=s1 | (0,1): R=s2 G=c B=s3
            //              (1,0): R=s3 G=c B=s2  | (1,1): R=s1 G=s0 B=c
            r4[p] = (qt == 0) ? c  : (qt == 1) ? s2 : (qt == 2) ? s3 : s1;
            g4[p] = (qi == qj) ? s0 : c;
            b4[p] = (qt == 0) ? s1 : (qt == 1) ? s3 : (qt == 2) ? s2 : c;
        }

        const int y = y0 + ry0 + dr;
        const size_t colbase = (size_t)(x0 + xs);
        v4f* __restrict__ oR = (v4f*)(out + ((size_t)(n * 3 + 0) * H + y) * W + colbase);
        v4f* __restrict__ oG = (v4f*)(out + ((size_t)(n * 3 + 1) * H + y) * W + colbase);
        v4f* __restrict__ oB = (v4f*)(out + ((size_t)(n * 3 + 2) * H + y) * W + colbase);
        v4f vR = { r4[0], r4[1], r4[2], r4[3] };
        v4f vG = { g4[0], g4[1], g4[2], g4[3] };
        v4f vB = { b4[0], b4[1], b4[2], b4[3] };
        __builtin_nontemporal_store(vR, oR);
        __builtin_nontemporal_store(vG, oG);
        __builtin_nontemporal_store(vB, oB);
    }
}

extern "C" void kernel_launch(void* const* d_in, const int* in_sizes, int n_in,
                              void* d_out, int out_size, void* d_ws, size_t ws_size,
                              hipStream_t stream) {
    const float* x  = (const float*)d_in[0];
    const int*   bp = (const int*)d_in[1];
    float* out = (float*)d_out;
    const int N = in_sizes[0] / (H * W);   // 16
    dim3 grid(W / TILE_W, H / TILE_H, N);  // (8, 32, 16)
    dim3 block(32, 8, 1);
    demosaic_kernel<<<grid, block, 0, stream>>>(x, bp, out);
}